// Round 7
// baseline (25.144 us; speedup 1.0000x reference)
//
#include <hip/hip_runtime.h>

typedef float f2 __attribute__((ext_vector_type(2)));

#define N_QUBITS 5
#define DIM 32
#define N_LAYERS 2

// CNOT permutation: new[i] = old[i ^ (cbit << pos_t)]
__host__ __device__ constexpr int cnot_apply(int i, int ctrl, int tgt) {
    const int pc = N_QUBITS - 1 - ctrl;
    const int pt = N_QUBITS - 1 - tgt;
    return i ^ (((i >> pc) & 1) << pt);
}
// Composed CNOT ring of a layer (round-1-verified): new[i] = old[layer_perm(i,r)]
__host__ __device__ constexpr int layer_perm(int i, int r) {
    int idx = i;
    for (int q = N_QUBITS - 1; q >= 0; --q)
        idx = cnot_apply(idx, q, (q + r) % N_QUBITS);
    return idx;
}

__device__ inline f2 cmul(f2 a, f2 b) {
    return f2{a.x * b.x - a.y * b.y, a.x * b.y + a.y * b.x};
}

__global__ __launch_bounds__(256, 4) void vqc_kernel(
    const float* __restrict__ x,      // (B, 5)
    const float* __restrict__ w,      // (2, 5, 3)
    const float* __restrict__ fc_w,   // (8, 5)
    const float* __restrict__ fc_b,   // (8,)
    float* __restrict__ out,          // (B, 8)
    int Btot)
{
    // ---- block-uniform gate precompute ----
    // layer 0: raw 8 coeffs per qubit (folded per-thread with RX).
    // layer 1: packed pk consts P,Q,R,S per qubit (round-2 butterfly form).
    __shared__ float s_g0[N_QUBITS][8];
    __shared__ f2    s_g1[N_QUBITS][4];
    __shared__ float s_fc_w[40];
    __shared__ float s_fc_b[8];

    const int t = threadIdx.x;
    if (t < N_LAYERS * N_QUBITS) {
        const float phi = w[t * 3 + 0];
        const float th  = w[t * 3 + 1];
        const float om  = w[t * 3 + 2];
        float s, c;   sincosf(0.5f * th, &s, &c);
        float sp, cp; sincosf(0.5f * (phi + om), &sp, &cp);
        float sm, cm; sincosf(0.5f * (phi - om), &sm, &cm);
        const float g00r =  cp * c, g00i = -sp * c;
        const float g01r = -cm * s, g01i = -sm * s;
        const float g10r =  cm * s, g10i = -sm * s;
        const float g11r =  cp * c, g11i =  sp * c;
        if (t < N_QUBITS) {           // layer 0, raw
            s_g0[t][0] = g00r; s_g0[t][1] = g00i;
            s_g0[t][2] = g01r; s_g0[t][3] = g01i;
            s_g0[t][4] = g10r; s_g0[t][5] = g10i;
            s_g0[t][6] = g11r; s_g0[t][7] = g11i;
        } else {                      // layer 1, packed
            const int q = t - N_QUBITS;
            s_g1[q][0] = f2{ g00r,  g00r};
            s_g1[q][1] = f2{-g00i,  g00i};
            s_g1[q][2] = f2{ g01r,  g01r};
            s_g1[q][3] = f2{-g01i,  g01i};
        }
    } else if (t >= 16 && t < 56) {
        s_fc_w[t - 16] = fc_w[t - 16];
    } else if (t >= 56 && t < 64) {
        s_fc_b[t - 56] = fc_b[t - 56];
    }
    __syncthreads();

    const int b = blockIdx.x * 256 + t;
    if (b >= Btot) return;

    // ---- per-qubit 2-vectors: v = Rot0_q * RX(x_q) * |0> ----
    // RX|0> = (c, -i s);  v0 = g00*c + g01*(-is); v1 = g10*c + g11*(-is)
    const float* xp = x + (size_t)b * 5;
    f2 v0[N_QUBITS], v1[N_QUBITS];
#pragma unroll
    for (int q = 0; q < N_QUBITS; ++q) {
        float s, c;
        __sincosf(0.5f * xp[q], &s, &c);
        v0[q] = f2{s_g0[q][0] * c + s_g0[q][3] * s,   // g00r*c + g01i*s
                   s_g0[q][1] * c - s_g0[q][2] * s};  // g00i*c - g01r*s
        v1[q] = f2{s_g0[q][4] * c + s_g0[q][7] * s,   // g10r*c + g11i*s
                   s_g0[q][5] * c - s_g0[q][6] * s};  // g10i*c - g11r*s
    }

    // ---- product state after layer 0: st = ⊗_q v_q (complex doubling) ----
    f2 st[DIM];
    st[0] = v0[0];
    st[16] = v1[0];   // qubit 0 at bit 4
#pragma unroll
    for (int q = 1; q < N_QUBITS; ++q) {
        const int stride = 1 << (4 - q);
#pragma unroll
        for (int k = 0; k < (1 << q); ++k) {
            const int m = k * (stride << 1);
            const f2 a = st[m];
            st[m + stride] = cmul(v1[q], a);
            st[m]          = cmul(v0[q], a);
        }
    }

    // ---- CNOT layer 0 perm (r=1): free register rename ----
    {
        f2 tmp[DIM];
#pragma unroll
        for (int i = 0; i < DIM; ++i) tmp[i] = st[layer_perm(i, 1)];
#pragma unroll
        for (int i = 0; i < DIM; ++i) st[i] = tmp[i];
    }

    // ---- layer 1: 5 Rot butterflies (packed f32, round-2 verbatim) ----
#pragma unroll
    for (int q = 0; q < N_QUBITS; ++q) {
        const f2 P = s_g1[q][0], Q = s_g1[q][1];
        const f2 R = s_g1[q][2], S = s_g1[q][3];
        const int stride = 1 << (4 - q);
        const int mask = stride - 1;
#pragma unroll
        for (int p = 0; p < DIM / 2; ++p) {
            const int ai = ((p & ~mask) << 1) | (p & mask);
            const int bi = ai + stride;
            const f2 a = st[ai], bb = st[bi];
            const f2 as = f2{a.y, a.x};
            const f2 bs = f2{bb.y, bb.x};
            st[ai] = P * a + Q * as + R * bb + S * bs;
            st[bi] = P * bb + S * as - R * a - Q * bs;
        }
    }

    // ---- probs, with final CNOT perm (r=2) folded in as a rename ----
    float pr[DIM];
#pragma unroll
    for (int i = 0; i < DIM; ++i) {
        const f2 sv = st[layer_perm(i, 2)];
        pr[i] = sv.x * sv.x + sv.y * sv.y;
    }

    // ---- expvals via Walsh-Hadamard partial-sum tree (round-2 verbatim) ----
    float v16[16], v8[8], v4[4], v2[2];
    float ev4 = 0.f, ev3 = 0.f, ev2 = 0.f, ev1 = 0.f, ev0;
#pragma unroll
    for (int j = 0; j < 16; ++j) { v16[j] = pr[2*j] + pr[2*j+1]; ev4 += pr[2*j] - pr[2*j+1]; }
#pragma unroll
    for (int j = 0; j < 8; ++j)  { v8[j] = v16[2*j] + v16[2*j+1]; ev3 += v16[2*j] - v16[2*j+1]; }
#pragma unroll
    for (int j = 0; j < 4; ++j)  { v4[j] = v8[2*j] + v8[2*j+1];  ev2 += v8[2*j] - v8[2*j+1]; }
#pragma unroll
    for (int j = 0; j < 2; ++j)  { v2[j] = v4[2*j] + v4[2*j+1];  ev1 += v4[2*j] - v4[2*j+1]; }
    ev0 = v2[0] - v2[1];
    const float ev[N_QUBITS] = {ev0, ev1, ev2, ev3, ev4};

    // ---- FC: out[b,j] = sum_q ev[q]*fc_w[j,q] + fc_b[j] ----
    float o[8];
#pragma unroll
    for (int j = 0; j < 8; ++j) {
        float acc = s_fc_b[j];
#pragma unroll
        for (int q = 0; q < 5; ++q) acc += ev[q] * s_fc_w[j * 5 + q];
        o[j] = acc;
    }
    float4* op = (float4*)(out + (size_t)b * 8);
    op[0] = make_float4(o[0], o[1], o[2], o[3]);
    op[1] = make_float4(o[4], o[5], o[6], o[7]);
}

extern "C" void kernel_launch(void* const* d_in, const int* in_sizes, int n_in,
                              void* d_out, int out_size, void* d_ws, size_t ws_size,
                              hipStream_t stream) {
    const float* x    = (const float*)d_in[0];
    const float* w    = (const float*)d_in[1];
    const float* fc_w = (const float*)d_in[2];
    const float* fc_b = (const float*)d_in[3];
    float* out = (float*)d_out;

    const int Btot = in_sizes[0] / N_QUBITS;   // 262144
    const int grid = (Btot + 255) / 256;
    hipLaunchKernelGGL(vqc_kernel, dim3(grid), dim3(256), 0, stream,
                       x, w, fc_w, fc_b, out, Btot);
}